// Round 5
// baseline (1621.803 us; speedup 1.0000x reference)
//
#include <hip/hip_runtime.h>
#include <hip/hip_bf16.h>

// MI355X / gfx950. B=4,S=1024,D=1024,H=8,DK=DV=128,DFF=2048,L=2.
// FP32 in/out. Compute: bf16x2-split MFMA (hi+lo, 3 MFMAs per product:
// hi*hi + hi*lo + lo*hi) for ~1e-5 relative accuracy — needed because the
// unscaled QK^T (score std ~20) makes softmax amplify bf16-level errors.
// Verified MFMA layouts: A[m=lane&15][k=quad*8+j], C/D col=lane&15,row=quad*4+reg.
// All scratch in a static __device__ array (192 MB), independent of ws_size.

typedef __bf16 bf16_t;
typedef bf16_t bf16x8 __attribute__((ext_vector_type(8)));
typedef bf16_t bf16x4v __attribute__((ext_vector_type(4)));
typedef float f32x4 __attribute__((ext_vector_type(4)));

#define MFMA16(a, b, c) __builtin_amdgcn_mfma_f32_16x16x32_bf16((a), (b), (c), 0, 0, 0)

__device__ __align__(256) unsigned char g_ws[(size_t)192 << 20];

#define MBOFF(x) ((size_t)(x) << 20)
#define OFF_X32 MBOFF(0)       // fp32 running residual (4M floats)
#define OFF_XB_HI MBOFF(16)    // bf16 hi/lo of x (GEMM A input)
#define OFF_XB_LO MBOFF(24)
#define OFF_Q_HI MBOFF(32)
#define OFF_Q_LO MBOFF(40)
#define OFF_K_HI MBOFF(48)
#define OFF_K_LO MBOFF(56)
#define OFF_V_HI MBOFF(64)
#define OFF_V_LO MBOFF(72)
#define OFF_VT_HI MBOFF(80)    // V transposed [bh,v,s]
#define OFF_VT_LO MBOFF(88)
#define OFF_CONC_HI MBOFF(96)  // attention output
#define OFF_CONC_LO MBOFF(104)
#define OFF_TMP MBOFF(112)     // fp32 proj/ffn2 output (4M floats)
#define OFF_H_HI MBOFF(128)    // ffn hidden (4096x2048)
#define OFF_H_LO MBOFF(144)
#define OFF_WQ_HI MBOFF(160)
#define OFF_WQ_LO MBOFF(162)
#define OFF_WK_HI MBOFF(164)
#define OFF_WK_LO MBOFF(166)
#define OFF_WV_HI MBOFF(168)
#define OFF_WV_LO MBOFF(170)
#define OFF_WO_HI MBOFF(172)
#define OFF_WO_LO MBOFF(174)
#define OFF_W1_HI MBOFF(176)
#define OFF_W1_LO MBOFF(180)
#define OFF_W2_HI MBOFF(184)
#define OFF_W2_LO MBOFF(188)

__device__ __forceinline__ void split2(float v, bf16_t& h, bf16_t& l) {
  h = (bf16_t)v;
  l = (bf16_t)(v - (float)h);
}

// ---------------------------------------------------------------------------
// Split GEMM: C[M,N] = A[M,K] @ Bt[N,K]^T, A/Bt stored as (hi,lo) bf16 pairs.
// EPI: 0 = fp32 out, 1 = split bf16 out, 2 = split out + bias + relu,
//      3 = fp32 out + bias
// 64x64 tile, BK=32, 256 threads (4 waves), wave w owns rows [w*16, w*16+16).
// Per k-step per wave: 10 ds_read_b128, 12 MFMAs.
// ---------------------------------------------------------------------------
template <int EPI>
__global__ __launch_bounds__(256) void gemm_bt(
    size_t a_hi_off, size_t a_lo_off, size_t b_hi_off, size_t b_lo_off,
    size_t c0_off, size_t c1_off, const float* __restrict__ bias,
    int M, int N, int K) {
  const bf16_t* Ah = (const bf16_t*)(g_ws + a_hi_off);
  const bf16_t* Al = (const bf16_t*)(g_ws + a_lo_off);
  const bf16_t* Bh = (const bf16_t*)(g_ws + b_hi_off);
  const bf16_t* Bl = (const bf16_t*)(g_ws + b_lo_off);
  float* Cf = (float*)(g_ws + c0_off);
  bf16_t* Ch = (bf16_t*)(g_ws + c0_off);
  bf16_t* Cl = (bf16_t*)(g_ws + c1_off);
  __shared__ __align__(16) bf16_t Ash[64 * 32];
  __shared__ __align__(16) bf16_t Asl[64 * 32];
  __shared__ __align__(16) bf16_t Bsh[64 * 32];
  __shared__ __align__(16) bf16_t Bsl[64 * 32];
  const int tid = threadIdx.x;
  const int wave = tid >> 6, lane = tid & 63;
  const int quad = lane >> 4, l16 = lane & 15;
  const int m0 = blockIdx.y * 64, n0 = blockIdx.x * 64;
  const int sr = tid >> 2, sc = (tid & 3) * 8;
  const long arow = (long)(m0 + sr) * K + sc;
  const long brow = (long)(n0 + sr) * K + sc;
  f32x4 acc[4] = {};

  for (int k0 = 0; k0 < K; k0 += 32) {
    *(bf16x8*)(Ash + sr * 32 + sc) = *(const bf16x8*)(Ah + arow + k0);
    *(bf16x8*)(Asl + sr * 32 + sc) = *(const bf16x8*)(Al + arow + k0);
    *(bf16x8*)(Bsh + sr * 32 + sc) = *(const bf16x8*)(Bh + brow + k0);
    *(bf16x8*)(Bsl + sr * 32 + sc) = *(const bf16x8*)(Bl + brow + k0);
    __syncthreads();
    bf16x8 ah = *(const bf16x8*)(Ash + (wave * 16 + l16) * 32 + quad * 8);
    bf16x8 al = *(const bf16x8*)(Asl + (wave * 16 + l16) * 32 + quad * 8);
#pragma unroll
    for (int nt = 0; nt < 4; ++nt) {
      bf16x8 bh = *(const bf16x8*)(Bsh + (nt * 16 + l16) * 32 + quad * 8);
      bf16x8 bl = *(const bf16x8*)(Bsl + (nt * 16 + l16) * 32 + quad * 8);
      acc[nt] = MFMA16(ah, bh, acc[nt]);
      acc[nt] = MFMA16(ah, bl, acc[nt]);
      acc[nt] = MFMA16(al, bh, acc[nt]);
    }
    __syncthreads();
  }

  const int row0 = m0 + wave * 16 + quad * 4;
#pragma unroll
  for (int nt = 0; nt < 4; ++nt) {
    const int col = n0 + nt * 16 + l16;
    float bv = (EPI >= 2) ? bias[col] : 0.0f;
#pragma unroll
    for (int r = 0; r < 4; ++r) {
      float v = acc[nt][r] + bv;
      if (EPI == 2) v = fmaxf(v, 0.0f);
      long off = (long)(row0 + r) * N + col;
      if (EPI == 0 || EPI == 3) {
        Cf[off] = v;
      } else {
        bf16_t h, l;
        split2(v, h, l);
        Ch[off] = h;
        Cl[off] = l;
      }
    }
  }
}

// ---------------------------------------------------------------------------
// Fused attention (flash-style; reference has NO 1/sqrt(dk) scale).
// grid = (S/64 q-tiles, B*H). block = 256 (4 waves); wave owns 16 q rows.
// Q,K: [b,s,h*128+k] split. VT: [bh,v,s] split. conc out: [b,s,h*128+v] split.
// Scores and P*V use the 3-MFMA split product.
// ---------------------------------------------------------------------------
__global__ __launch_bounds__(256) void attn_kernel(const float* __restrict__ mask) {
  const int S = 1024;
  const bf16_t* Qh = (const bf16_t*)(g_ws + OFF_Q_HI);
  const bf16_t* Ql = (const bf16_t*)(g_ws + OFF_Q_LO);
  const bf16_t* Kh = (const bf16_t*)(g_ws + OFF_K_HI);
  const bf16_t* Kl = (const bf16_t*)(g_ws + OFF_K_LO);
  const bf16_t* Vth = (const bf16_t*)(g_ws + OFF_VT_HI);
  const bf16_t* Vtl = (const bf16_t*)(g_ws + OFF_VT_LO);
  bf16_t* conch = (bf16_t*)(g_ws + OFF_CONC_HI);
  bf16_t* concl = (bf16_t*)(g_ws + OFF_CONC_LO);
  __shared__ __align__(16) bf16_t Psh[4][16 * 64];
  __shared__ __align__(16) bf16_t Psl[4][16 * 64];
  const int tid = threadIdx.x;
  const int wave = tid >> 6, lane = tid & 63;
  const int quad = lane >> 4, l16 = lane & 15;
  const int q0 = blockIdx.x * 64;
  const int bh_i = blockIdx.y, b = bh_i >> 3, h = bh_i & 7;
  const long qkbase = (long)b * S * 1024 + h * 128;
  const long vbase = (long)bh_i * 128 * S;

  bf16x8 qfh[4], qfl[4];
  const int qrow = q0 + wave * 16 + l16;
#pragma unroll
  for (int ks = 0; ks < 4; ++ks) {
    qfh[ks] = *(const bf16x8*)(Qh + qkbase + (long)qrow * 1024 + ks * 32 + quad * 8);
    qfl[ks] = *(const bf16x8*)(Ql + qkbase + (long)qrow * 1024 + ks * 32 + quad * 8);
  }

  f32x4 o[8] = {};
  float mi[4] = {-1e30f, -1e30f, -1e30f, -1e30f};
  float li[4] = {0.f, 0.f, 0.f, 0.f};

  for (int t0 = 0; t0 < S; t0 += 64) {
    // S = Q @ K^T (split product)
    f32x4 s4[4] = {};
#pragma unroll
    for (int nt = 0; nt < 4; ++nt) {
      const long krow = qkbase + (long)(t0 + nt * 16 + l16) * 1024 + quad * 8;
#pragma unroll
      for (int ks = 0; ks < 4; ++ks) {
        bf16x8 kfh = *(const bf16x8*)(Kh + krow + ks * 32);
        bf16x8 kfl = *(const bf16x8*)(Kl + krow + ks * 32);
        s4[nt] = MFMA16(qfh[ks], kfh, s4[nt]);
        s4[nt] = MFMA16(qfh[ks], kfl, s4[nt]);
        s4[nt] = MFMA16(qfl[ks], kfh, s4[nt]);
      }
    }
    // mask: A = m*A + (1-m)*MASK_VALUE (column mask; MASK_VALUE=-1e-30)
#pragma unroll
    for (int nt = 0; nt < 4; ++nt) {
      float mv = mask[b * S + t0 + nt * 16 + l16];
      float addv = (1.0f - mv) * (-1e-30f);
#pragma unroll
      for (int r = 0; r < 4; ++r) s4[nt][r] = mv * s4[nt][r] + addv;
    }
    // online softmax; row r lives on the 16 lanes of this quad
#pragma unroll
    for (int r = 0; r < 4; ++r) {
      float mx = fmaxf(fmaxf(s4[0][r], s4[1][r]), fmaxf(s4[2][r], s4[3][r]));
#pragma unroll
      for (int off = 1; off < 16; off <<= 1) mx = fmaxf(mx, __shfl_xor(mx, off, 64));
      float mnew = fmaxf(mi[r], mx);
      float alpha = __expf(mi[r] - mnew);
      float rs = 0.0f;
#pragma unroll
      for (int nt = 0; nt < 4; ++nt) {
        float p = __expf(s4[nt][r] - mnew);
        s4[nt][r] = p;
        rs += p;
      }
#pragma unroll
      for (int off = 1; off < 16; off <<= 1) rs += __shfl_xor(rs, off, 64);
      li[r] = li[r] * alpha + rs;
      mi[r] = mnew;
#pragma unroll
      for (int on = 0; on < 8; ++on) o[on][r] *= alpha;
    }
    // P: C-layout -> LDS (split) -> A-layout
    __syncthreads();
#pragma unroll
    for (int nt = 0; nt < 4; ++nt)
#pragma unroll
      for (int r = 0; r < 4; ++r) {
        bf16_t ph, pl;
        split2(s4[nt][r], ph, pl);
        Psh[wave][(quad * 4 + r) * 64 + nt * 16 + l16] = ph;
        Psl[wave][(quad * 4 + r) * 64 + nt * 16 + l16] = pl;
      }
    __syncthreads();
    bf16x8 pfh[2], pfl[2];
#pragma unroll
    for (int k2 = 0; k2 < 2; ++k2) {
      pfh[k2] = *(const bf16x8*)(&Psh[wave][l16 * 64 + k2 * 32 + quad * 8]);
      pfl[k2] = *(const bf16x8*)(&Psl[wave][l16 * 64 + k2 * 32 + quad * 8]);
    }
    // O += P @ V (split product; VT rows are v, cols t)
#pragma unroll
    for (int k2 = 0; k2 < 2; ++k2) {
#pragma unroll
      for (int on = 0; on < 8; ++on) {
        const long vrow = vbase + (long)(on * 16 + l16) * S + t0 + k2 * 32 + quad * 8;
        bf16x8 vfh = *(const bf16x8*)(Vth + vrow);
        bf16x8 vfl = *(const bf16x8*)(Vtl + vrow);
        o[on] = MFMA16(pfh[k2], vfh, o[on]);
        o[on] = MFMA16(pfh[k2], vfl, o[on]);
        o[on] = MFMA16(pfl[k2], vfh, o[on]);
      }
    }
  }
  // epilogue: divide by l, write split conc[b, s, h*128+v]
  const int srow = q0 + wave * 16 + quad * 4;
#pragma unroll
  for (int r = 0; r < 4; ++r) {
    float inv = 1.0f / li[r];
#pragma unroll
    for (int on = 0; on < 8; ++on) {
      float v = o[on][r] * inv;
      bf16_t hh, ll;
      split2(v, hh, ll);
      long off = (long)(b * S + srow + r) * 1024 + h * 128 + on * 16 + l16;
      conch[off] = hh;
      concl[off] = ll;
    }
  }
}

// ---------------------------------------------------------------------------
// Residual + LayerNorm. One block per row (D=1024). Reads X32 + TMP (fp32),
// writes X32 + split XB; if extf != null (final) writes fp32 there instead.
// ---------------------------------------------------------------------------
__global__ __launch_bounds__(256) void ln_kernel(
    const float* __restrict__ gamma, const float* __restrict__ beta, int gidx,
    float* __restrict__ extf) {
  const float* xres = (const float*)(g_ws + OFF_X32);
  const float* y = (const float*)(g_ws + OFF_TMP);
  float* xout = (float*)(g_ws + OFF_X32);
  bf16_t* xbh = (bf16_t*)(g_ws + OFF_XB_HI);
  bf16_t* xbl = (bf16_t*)(g_ws + OFF_XB_LO);
  const int row = blockIdx.x, tid = threadIdx.x;
  const int wave = tid >> 6, lane = tid & 63;
  const long base = (long)row * 1024 + tid * 4;
  float4 xv = *(const float4*)(xres + base);
  float4 yv = *(const float4*)(y + base);
  float v0 = xv.x + yv.x, v1 = xv.y + yv.y, v2 = xv.z + yv.z, v3 = xv.w + yv.w;
  float s1 = v0 + v1 + v2 + v3;
  float s2 = v0 * v0 + v1 * v1 + v2 * v2 + v3 * v3;
#pragma unroll
  for (int off = 1; off < 64; off <<= 1) {
    s1 += __shfl_xor(s1, off, 64);
    s2 += __shfl_xor(s2, off, 64);
  }
  __shared__ __align__(16) float r1[4], r2[4];
  if (lane == 0) { r1[wave] = s1; r2[wave] = s2; }
  __syncthreads();
  s1 = r1[0] + r1[1] + r1[2] + r1[3];
  s2 = r2[0] + r2[1] + r2[2] + r2[3];
  const float mean = s1 * (1.0f / 1024.0f);
  float var = s2 * (1.0f / 1024.0f) - mean * mean;
  var = fmaxf(var, 0.0f);
  const float inv = rsqrtf(var + 1e-14f);
  const float g = gamma[gidx], be = beta[gidx];
  float o0 = (v0 - mean) * inv * g + be;
  float o1 = (v1 - mean) * inv * g + be;
  float o2 = (v2 - mean) * inv * g + be;
  float o3 = (v3 - mean) * inv * g + be;
  float4 ov = {o0, o1, o2, o3};
  *(float4*)(xout + base) = ov;
  if (extf) {
    *(float4*)(extf + base) = ov;
  } else {
    bf16_t h0, l0, h1, l1, h2, l2, h3, l3;
    split2(o0, h0, l0); split2(o1, h1, l1);
    split2(o2, h2, l2); split2(o3, h3, l3);
    bf16x4v hv = {h0, h1, h2, h3};
    bf16x4v lv = {l0, l1, l2, l3};
    *(bf16x4v*)(xbh + base) = hv;
    *(bf16x4v*)(xbl + base) = lv;
  }
}

// fp32 input x -> X32 (fp32 copy) + split XB, 4 elems/thread
__global__ __launch_bounds__(256) void cast_f2b(const float* __restrict__ in) {
  float* out = (float*)(g_ws + OFF_X32);
  bf16_t* outh = (bf16_t*)(g_ws + OFF_XB_HI);
  bf16_t* outl = (bf16_t*)(g_ws + OFF_XB_LO);
  long i = ((long)blockIdx.x * 256 + threadIdx.x) * 4;
  float4 v = *(const float4*)(in + i);
  *(float4*)(out + i) = v;
  bf16_t h0, l0, h1, l1, h2, l2, h3, l3;
  split2(v.x, h0, l0); split2(v.y, h1, l1);
  split2(v.z, h2, l2); split2(v.w, h3, l3);
  bf16x4v hv = {h0, h1, h2, h3};
  bf16x4v lv = {l0, l1, l2, l3};
  *(bf16x4v*)(outh + i) = hv;
  *(bf16x4v*)(outl + i) = lv;
}

// V[b,s,h*128+v] (split) -> VT[bh,v,s] (split)
__global__ __launch_bounds__(256) void v_trans() {
  const bf16_t* Vh = (const bf16_t*)(g_ws + OFF_V_HI);
  const bf16_t* Vl = (const bf16_t*)(g_ws + OFF_V_LO);
  bf16_t* Vth = (bf16_t*)(g_ws + OFF_VT_HI);
  bf16_t* Vtl = (bf16_t*)(g_ws + OFF_VT_LO);
  int idx = blockIdx.x * 256 + threadIdx.x;  // 4M
  int s = idx & 1023;
  int r = idx >> 10;  // bh*128 + v
  int v = r & 127, h = (r >> 7) & 7, b = r >> 10;
  long src = (long)(b * 1024 + s) * 1024 + h * 128 + v;
  Vth[idx] = Vh[src];
  Vtl[idx] = Vl[src];
}

// Wq[h,d,dk] fp32 -> split Wt[n=h*128+dk, d]
__global__ __launch_bounds__(256) void wt_qkv(const float* __restrict__ in,
                                              size_t hi_off, size_t lo_off) {
  bf16_t* oh = (bf16_t*)(g_ws + hi_off);
  bf16_t* ol = (bf16_t*)(g_ws + lo_off);
  int idx = blockIdx.x * 256 + threadIdx.x;
  int d = idx & 1023, n = idx >> 10;
  float v = in[(n >> 7) * 131072 + d * 128 + (n & 127)];
  bf16_t h, l;
  split2(v, h, l);
  oh[idx] = h;
  ol[idx] = l;
}

// generic transpose + split: out[c*R + r] = in[r*C + c]
__global__ __launch_bounds__(256) void wt_gen(const float* __restrict__ in,
                                              size_t hi_off, size_t lo_off,
                                              int R, int C) {
  bf16_t* oh = (bf16_t*)(g_ws + hi_off);
  bf16_t* ol = (bf16_t*)(g_ws + lo_off);
  int idx = blockIdx.x * 256 + threadIdx.x;  // idx = c*R + r
  int r = idx % R, c = idx / R;
  float v = in[(long)r * C + c];
  bf16_t h, l;
  split2(v, h, l);
  oh[idx] = h;
  ol[idx] = l;
}

// ---------------------------------------------------------------------------
extern "C" void kernel_launch(void* const* d_in, const int* in_sizes, int n_in,
                              void* d_out, int out_size, void* d_ws, size_t ws_size,
                              hipStream_t stream) {
  const float* x_in = (const float*)d_in[0];
  const float* mask = (const float*)d_in[1];
  const float* Wq = (const float*)d_in[2];
  const float* Wk = (const float*)d_in[3];
  const float* Wv = (const float*)d_in[4];
  const float* Wo = (const float*)d_in[5];
  const float* W1 = (const float*)d_in[6];
  const float* b1 = (const float*)d_in[7];
  const float* W2 = (const float*)d_in[8];
  const float* b2 = (const float*)d_in[9];
  const float* gamma = (const float*)d_in[10];
  const float* beta = (const float*)d_in[11];
  float* out = (float*)d_out;
  (void)d_ws; (void)ws_size; (void)in_sizes; (void)n_in; (void)out_size;

  cast_f2b<<<4096, 256, 0, stream>>>(x_in);

  for (int l = 0; l < 2; ++l) {
    wt_qkv<<<4096, 256, 0, stream>>>(Wq + (long)l * 1048576, OFF_WQ_HI, OFF_WQ_LO);
    wt_qkv<<<4096, 256, 0, stream>>>(Wk + (long)l * 1048576, OFF_WK_HI, OFF_WK_LO);
    wt_qkv<<<4096, 256, 0, stream>>>(Wv + (long)l * 1048576, OFF_WV_HI, OFF_WV_LO);
    wt_gen<<<4096, 256, 0, stream>>>(Wo + (long)l * 1048576, OFF_WO_HI, OFF_WO_LO, 1024, 1024);
    wt_gen<<<8192, 256, 0, stream>>>(W1 + (long)l * 2097152, OFF_W1_HI, OFF_W1_LO, 1024, 2048);
    wt_gen<<<8192, 256, 0, stream>>>(W2 + (long)l * 2097152, OFF_W2_HI, OFF_W2_LO, 2048, 1024);

    dim3 g1(16, 64);
    gemm_bt<1><<<g1, 256, 0, stream>>>(OFF_XB_HI, OFF_XB_LO, OFF_WQ_HI, OFF_WQ_LO,
                                       OFF_Q_HI, OFF_Q_LO, nullptr, 4096, 1024, 1024);
    gemm_bt<1><<<g1, 256, 0, stream>>>(OFF_XB_HI, OFF_XB_LO, OFF_WK_HI, OFF_WK_LO,
                                       OFF_K_HI, OFF_K_LO, nullptr, 4096, 1024, 1024);
    gemm_bt<1><<<g1, 256, 0, stream>>>(OFF_XB_HI, OFF_XB_LO, OFF_WV_HI, OFF_WV_LO,
                                       OFF_V_HI, OFF_V_LO, nullptr, 4096, 1024, 1024);
    v_trans<<<16384, 256, 0, stream>>>();
    attn_kernel<<<dim3(16, 32), 256, 0, stream>>>(mask);
    gemm_bt<0><<<g1, 256, 0, stream>>>(OFF_CONC_HI, OFF_CONC_LO, OFF_WO_HI, OFF_WO_LO,
                                       OFF_TMP, 0, nullptr, 4096, 1024, 1024);
    ln_kernel<<<4096, 256, 0, stream>>>(gamma, beta, 2 * l, nullptr);
    gemm_bt<2><<<dim3(32, 64), 256, 0, stream>>>(OFF_XB_HI, OFF_XB_LO, OFF_W1_HI, OFF_W1_LO,
                                                 OFF_H_HI, OFF_H_LO, b1 + l * 2048,
                                                 4096, 2048, 1024);
    gemm_bt<3><<<g1, 256, 0, stream>>>(OFF_H_HI, OFF_H_LO, OFF_W2_HI, OFF_W2_LO,
                                       OFF_TMP, 0, b2 + l * 1024, 4096, 1024, 2048);
    ln_kernel<<<4096, 256, 0, stream>>>(gamma, beta, 2 * l + 1,
                                        (l == 1) ? out : nullptr);
  }
}

// Round 7
// 879.586 us; speedup vs baseline: 1.8438x; 1.8438x over previous
//
#include <hip/hip_runtime.h>
#include <hip/hip_bf16.h>

// MI355X / gfx950. B=4,S=1024,D=1024,H=8,DK=DV=128,DFF=2048,L=2.
// FP32 in/out. bf16x2-split MFMA (hi*hi + hi*lo + lo*hi) for ~1e-5 relative
// accuracy (unscaled QK^T, score std ~20, sharp softmax).
// Round-7 fix: K-tile staging swizzle must use the ACTUAL staged row
// (sKrow + j*4), not the j=0 row — (row&7) changes with j*4. V staging was
// accidentally correct (j*8 preserves row&7). GEMM swizzle verified.
// Verified MFMA layouts: A[m=lane&15][k=quad*8+j], C/D col=lane&15,row=quad*4+reg.

typedef __bf16 bf16_t;
typedef bf16_t bf16x8 __attribute__((ext_vector_type(8)));
typedef bf16_t bf16x4v __attribute__((ext_vector_type(4)));
typedef float f32x4 __attribute__((ext_vector_type(4)));

#define MFMA16(a, b, c) __builtin_amdgcn_mfma_f32_16x16x32_bf16((a), (b), (c), 0, 0, 0)

__device__ __align__(256) unsigned char g_ws[(size_t)192 << 20];

#define MBOFF(x) ((size_t)(x) << 20)
#define OFF_X32 MBOFF(0)        // fp32 running residual (4M floats)
#define OFF_XB_HI MBOFF(16)     // bf16 hi/lo of x (GEMM A input)
#define OFF_XB_LO MBOFF(24)
#define OFF_QKV_HI MBOFF(32)    // fused QKV out [4096][3072]
#define OFF_QKV_LO MBOFF(56)
#define OFF_VT_HI MBOFF(80)     // V transposed [bh,v,s]
#define OFF_VT_LO MBOFF(88)
#define OFF_CONC_HI MBOFF(96)   // attention output [b,s,h*128+v]
#define OFF_CONC_LO MBOFF(104)
#define OFF_TMP MBOFF(112)      // fp32 proj/ffn2 output (4M floats)
#define OFF_H_HI MBOFF(128)     // ffn hidden (4096x2048)
#define OFF_H_LO MBOFF(144)
#define OFF_WQKV_HI MBOFF(160)  // [3072][1024]
#define OFF_WQKV_LO MBOFF(166)
#define OFF_WO_HI MBOFF(172)
#define OFF_WO_LO MBOFF(174)
#define OFF_W1_HI MBOFF(176)
#define OFF_W1_LO MBOFF(180)
#define OFF_W2_HI MBOFF(184)
#define OFF_W2_LO MBOFF(188)

__device__ __forceinline__ void split2(float v, bf16_t& h, bf16_t& l) {
  h = (bf16_t)v;
  l = (bf16_t)(v - (float)h);
}

// async global->LDS, 16 bytes per lane; LDS dest = wave-uniform base + lane*16
__device__ __forceinline__ void gl2lds16(const bf16_t* g, bf16_t* l) {
  __builtin_amdgcn_global_load_lds(
      (const __attribute__((address_space(1))) unsigned int*)(g),
      (__attribute__((address_space(3))) unsigned int*)(l), 16, 0, 0);
}

// ---------------------------------------------------------------------------
// Split GEMM, m97-style: C[M,N] = A[M,K] @ Bt[N,K]^T, (hi,lo) bf16 pairs.
// 128x128 tile, BK=32, 512 threads (8 waves). Wave w: m-group (w&3)*32,
// n-group (w>>2)*64. Staging via global_load_lds with XOR chunk swizzle
// (slot(row,c) holds global chunk c ^ ((row>>1)&3)).
// EPI: 0 = fp32 out, 1 = split out, 2 = split out + bias + relu, 3 = fp32+bias
// ---------------------------------------------------------------------------
template <int EPI>
__global__ __launch_bounds__(512) void gemm_bt(
    size_t a_hi, size_t a_lo, size_t b_hi, size_t b_lo,
    size_t c0o, size_t c1o, const float* __restrict__ bias, int M, int N, int K) {
  const bf16_t* Ah = (const bf16_t*)(g_ws + a_hi);
  const bf16_t* Al = (const bf16_t*)(g_ws + a_lo);
  const bf16_t* Bh = (const bf16_t*)(g_ws + b_hi);
  const bf16_t* Bl = (const bf16_t*)(g_ws + b_lo);
  float* Cf = (float*)(g_ws + c0o);
  bf16_t* Ch = (bf16_t*)(g_ws + c0o);
  bf16_t* Cl = (bf16_t*)(g_ws + c1o);
  __shared__ __align__(16) bf16_t Ash[128 * 32];
  __shared__ __align__(16) bf16_t Asl[128 * 32];
  __shared__ __align__(16) bf16_t Bsh[128 * 32];
  __shared__ __align__(16) bf16_t Bsl[128 * 32];
  const int tid = threadIdx.x;
  const int wave = tid >> 6, lane = tid & 63;
  const int quad = lane >> 4, l16 = lane & 15;
  const int wm = wave & 3, wn = wave >> 2;
  const int m0 = blockIdx.y * 128, n0 = blockIdx.x * 128;
  // staging: wave covers rows wave*16..+15, lane -> (row lane>>2, chunk lane&3)
  const int srow = wave * 16 + (lane >> 2);
  const int scp = (lane & 3) ^ ((srow >> 1) & 3);
  const long agoff = (long)(m0 + srow) * K + scp * 8;
  const long bgoff = (long)(n0 + srow) * K + scp * 8;
  bf16_t* ldsA = Ash + wave * 512;  // wave's 16 rows * 32 elems
  bf16_t* ldsAl = Asl + wave * 512;
  bf16_t* ldsB = Bsh + wave * 512;
  bf16_t* ldsBl = Bsl + wave * 512;
  // frag read offsets (swizzled)
  int aOff[2], bOff[4];
#pragma unroll
  for (int mt = 0; mt < 2; ++mt) {
    int R = wm * 32 + mt * 16 + l16;
    aOff[mt] = R * 32 + ((quad ^ ((R >> 1) & 3)) * 8);
  }
#pragma unroll
  for (int nt = 0; nt < 4; ++nt) {
    int R = wn * 64 + nt * 16 + l16;
    bOff[nt] = R * 32 + ((quad ^ ((R >> 1) & 3)) * 8);
  }
  f32x4 acc[2][4] = {};

  for (int k0 = 0; k0 < K; k0 += 32) {
    gl2lds16(Ah + agoff + k0, ldsA);
    gl2lds16(Al + agoff + k0, ldsAl);
    gl2lds16(Bh + bgoff + k0, ldsB);
    gl2lds16(Bl + bgoff + k0, ldsBl);
    __syncthreads();
    bf16x8 ah[2], al[2], bhf[4], blf[4];
#pragma unroll
    for (int mt = 0; mt < 2; ++mt) {
      ah[mt] = *(const bf16x8*)(Ash + aOff[mt]);
      al[mt] = *(const bf16x8*)(Asl + aOff[mt]);
    }
#pragma unroll
    for (int nt = 0; nt < 4; ++nt) {
      bhf[nt] = *(const bf16x8*)(Bsh + bOff[nt]);
      blf[nt] = *(const bf16x8*)(Bsl + bOff[nt]);
    }
#pragma unroll
    for (int mt = 0; mt < 2; ++mt)
#pragma unroll
      for (int nt = 0; nt < 4; ++nt) {
        acc[mt][nt] = MFMA16(ah[mt], bhf[nt], acc[mt][nt]);
        acc[mt][nt] = MFMA16(ah[mt], blf[nt], acc[mt][nt]);
        acc[mt][nt] = MFMA16(al[mt], bhf[nt], acc[mt][nt]);
      }
    __syncthreads();
  }

#pragma unroll
  for (int mt = 0; mt < 2; ++mt) {
    const int row0 = m0 + wm * 32 + mt * 16 + quad * 4;
#pragma unroll
    for (int nt = 0; nt < 4; ++nt) {
      const int col = n0 + wn * 64 + nt * 16 + l16;
      float bv = (EPI >= 2) ? bias[col] : 0.0f;
#pragma unroll
      for (int r = 0; r < 4; ++r) {
        float v = acc[mt][nt][r] + bv;
        if (EPI == 2) v = fmaxf(v, 0.0f);
        long off = (long)(row0 + r) * N + col;
        if (EPI == 0 || EPI == 3) {
          Cf[off] = v;
        } else {
          bf16_t h, l;
          split2(v, h, l);
          Ch[off] = h;
          Cl[off] = l;
        }
      }
    }
  }
}

// ---------------------------------------------------------------------------
// Fused attention (flash-style; reference has NO 1/sqrt(dk) scale).
// grid = (S/64 q-tiles, B*H). block 256 (4 waves); wave owns 16 q rows.
// Q,K from fused QKV [b,s][3072] (Q at h*128, K at 1024+h*128), split.
// VT: [bh,v,s] split. K/V tiles staged to LDS via swizzled global_load_lds.
// QK: 3-MFMA split. PV: P-hi only (x V hi+lo), P round-trip per-wave (no
// barrier: DS ops are in-order within a wave). conc out split.
// ---------------------------------------------------------------------------
__global__ __launch_bounds__(256) void attn_kernel(const float* __restrict__ mask) {
  const bf16_t* QKVh = (const bf16_t*)(g_ws + OFF_QKV_HI);
  const bf16_t* QKVl = (const bf16_t*)(g_ws + OFF_QKV_LO);
  const bf16_t* VTh = (const bf16_t*)(g_ws + OFF_VT_HI);
  const bf16_t* VTl = (const bf16_t*)(g_ws + OFF_VT_LO);
  bf16_t* conch = (bf16_t*)(g_ws + OFF_CONC_HI);
  bf16_t* concl = (bf16_t*)(g_ws + OFF_CONC_LO);
  __shared__ __align__(16) bf16_t Ksh[64 * 128];
  __shared__ __align__(16) bf16_t Ksl[64 * 128];
  __shared__ __align__(16) bf16_t Vsh[128 * 64];
  __shared__ __align__(16) bf16_t Vsl[128 * 64];
  __shared__ __align__(16) bf16_t Ps[4][16 * 72];  // P hi, +8 pad per row
  const int tid = threadIdx.x;
  const int wave = tid >> 6, lane = tid & 63;
  const int quad = lane >> 4, l16 = lane & 15;
  const int q0 = blockIdx.x * 64;
  const int bh = blockIdx.y, b = bh >> 3, h = bh & 7;

  // Q fragments (held in registers for the whole kernel)
  bf16x8 qfh[4], qfl[4];
  const long qgbase = ((long)(b * 1024) + q0 + wave * 16 + l16) * 3072 + h * 128;
#pragma unroll
  for (int ks = 0; ks < 4; ++ks) {
    qfh[ks] = *(const bf16x8*)(QKVh + qgbase + ks * 32 + quad * 8);
    qfl[ks] = *(const bf16x8*)(QKVl + qgbase + ks * 32 + quad * 8);
  }

  // staging coords.
  // K tile: 64 rows x 128 elems (16 chunks of 8); swizzle slot = chunk ^ (row&7)*2.
  const int sKrow4 = wave * 16 + (lane >> 4);  // + j*4 = actual row
  // V tile: 128 rows x 64 elems (8 chunks of 8); swizzle slot = chunk ^ (row&7).
  const int sVrow = wave * 32 + (lane >> 3);   // + j*8 (row&7 invariant)
  const int sVc = (lane & 7) ^ (sVrow & 7);
  const long vgbase = (long)bh * 131072 + (long)sVrow * 1024 + sVc * 8;

  f32x4 o[8] = {};
  float mi[4] = {-1e30f, -1e30f, -1e30f, -1e30f};
  float li[4] = {0.f, 0.f, 0.f, 0.f};

  for (int t0 = 0; t0 < 1024; t0 += 64) {
    // ---- stage K (8 instr) + V (8 instr) per wave ----
#pragma unroll
    for (int j = 0; j < 4; ++j) {
      const int r = sKrow4 + j * 4;  // actual row in the 64-row K tile
      const int c = (lane & 15) ^ ((r & 7) * 2);
      const long kg = ((long)(b * 1024) + t0 + r) * 3072 + 1024 + h * 128 + c * 8;
      gl2lds16(QKVh + kg, Ksh + (wave * 16 + j * 4) * 128);
      gl2lds16(QKVl + kg, Ksl + (wave * 16 + j * 4) * 128);
    }
#pragma unroll
    for (int j = 0; j < 4; ++j) {
      const long vg = vgbase + (long)(j * 8) * 1024 + t0;
      gl2lds16(VTh + vg, Vsh + (wave * 32 + j * 8) * 64);
      gl2lds16(VTl + vg, Vsl + (wave * 32 + j * 8) * 64);
    }
    __syncthreads();
    // ---- S = Q @ K^T (split) ----
    f32x4 s4[4] = {};
#pragma unroll
    for (int nt = 0; nt < 4; ++nt) {
      const int krow = nt * 16 + l16;
      const int ksw = (krow & 7) * 2;
#pragma unroll
      for (int ks = 0; ks < 4; ++ks) {
        const int so = krow * 128 + (((ks * 4 + quad) ^ ksw) * 8);
        bf16x8 kfh = *(const bf16x8*)(Ksh + so);
        bf16x8 kfl = *(const bf16x8*)(Ksl + so);
        s4[nt] = MFMA16(qfh[ks], kfh, s4[nt]);
        s4[nt] = MFMA16(qfh[ks], kfl, s4[nt]);
        s4[nt] = MFMA16(qfl[ks], kfh, s4[nt]);
      }
    }
    // mask: A = m*A + (1-m)*(-1e-30)
#pragma unroll
    for (int nt = 0; nt < 4; ++nt) {
      float mv = mask[b * 1024 + t0 + nt * 16 + l16];
      float addv = (1.0f - mv) * (-1e-30f);
#pragma unroll
      for (int r = 0; r < 4; ++r) s4[nt][r] = mv * s4[nt][r] + addv;
    }
    // online softmax (row r on the 16 lanes of this quad)
#pragma unroll
    for (int r = 0; r < 4; ++r) {
      float mx = fmaxf(fmaxf(s4[0][r], s4[1][r]), fmaxf(s4[2][r], s4[3][r]));
#pragma unroll
      for (int off = 1; off < 16; off <<= 1) mx = fmaxf(mx, __shfl_xor(mx, off, 64));
      float mnew = fmaxf(mi[r], mx);
      float alpha = __expf(mi[r] - mnew);
      float rs = 0.0f;
#pragma unroll
      for (int nt = 0; nt < 4; ++nt) {
        float p = __expf(s4[nt][r] - mnew);
        s4[nt][r] = p;
        rs += p;
      }
#pragma unroll
      for (int off = 1; off < 16; off <<= 1) rs += __shfl_xor(rs, off, 64);
      li[r] = li[r] * alpha + rs;
      mi[r] = mnew;
#pragma unroll
      for (int on = 0; on < 8; ++on) o[on][r] *= alpha;
    }
    // P: C-layout -> per-wave LDS -> A-layout (DS in-order per wave, no barrier)
#pragma unroll
    for (int nt = 0; nt < 4; ++nt)
#pragma unroll
      for (int r = 0; r < 4; ++r)
        Ps[wave][(quad * 4 + r) * 72 + nt * 16 + l16] = (bf16_t)s4[nt][r];
    bf16x8 pf[2];
#pragma unroll
    for (int k2 = 0; k2 < 2; ++k2)
      pf[k2] = *(const bf16x8*)(&Ps[wave][l16 * 72 + k2 * 32 + quad * 8]);
    // ---- O += P @ V (P-hi x (V-hi + V-lo)) ----
#pragma unroll
    for (int k2 = 0; k2 < 2; ++k2) {
#pragma unroll
      for (int on = 0; on < 8; ++on) {
        const int vrow = on * 16 + l16;
        const int so = vrow * 64 + (((k2 * 4 + quad) ^ (vrow & 7)) * 8);
        bf16x8 vfh = *(const bf16x8*)(Vsh + so);
        bf16x8 vfl = *(const bf16x8*)(Vsl + so);
        o[on] = MFMA16(pf[k2], vfh, o[on]);
        o[on] = MFMA16(pf[k2], vfl, o[on]);
      }
    }
    __syncthreads();
  }
  // epilogue: divide by l, write split conc[b, s, h*128+v]
  const int srow_o = q0 + wave * 16 + quad * 4;
#pragma unroll
  for (int r = 0; r < 4; ++r) {
    float inv = 1.0f / li[r];
#pragma unroll
    for (int on = 0; on < 8; ++on) {
      float v = o[on][r] * inv;
      bf16_t hh, ll;
      split2(v, hh, ll);
      long off = (long)(b * 1024 + srow_o + r) * 1024 + h * 128 + on * 16 + l16;
      conch[off] = hh;
      concl[off] = ll;
    }
  }
}

// ---------------------------------------------------------------------------
// Residual + LayerNorm. One block per row (D=1024). Reads X32 + TMP (fp32),
// writes X32 + split XB; if extf != null (final) writes fp32 there instead.
// ---------------------------------------------------------------------------
__global__ __launch_bounds__(256) void ln_kernel(
    const float* __restrict__ gamma, const float* __restrict__ beta, int gidx,
    float* __restrict__ extf) {
  const float* xres = (const float*)(g_ws + OFF_X32);
  const float* y = (const float*)(g_ws + OFF_TMP);
  float* xout = (float*)(g_ws + OFF_X32);
  bf16_t* xbh = (bf16_t*)(g_ws + OFF_XB_HI);
  bf16_t* xbl = (bf16_t*)(g_ws + OFF_XB_LO);
  const int row = blockIdx.x, tid = threadIdx.x;
  const int wave = tid >> 6, lane = tid & 63;
  const long base = (long)row * 1024 + tid * 4;
  float4 xv = *(const float4*)(xres + base);
  float4 yv = *(const float4*)(y + base);
  float v0 = xv.x + yv.x, v1 = xv.y + yv.y, v2 = xv.z + yv.z, v3 = xv.w + yv.w;
  float s1 = v0 + v1 + v2 + v3;
  float s2 = v0 * v0 + v1 * v1 + v2 * v2 + v3 * v3;
#pragma unroll
  for (int off = 1; off < 64; off <<= 1) {
    s1 += __shfl_xor(s1, off, 64);
    s2 += __shfl_xor(s2, off, 64);
  }
  __shared__ __align__(16) float r1[4], r2[4];
  if (lane == 0) { r1[wave] = s1; r2[wave] = s2; }
  __syncthreads();
  s1 = r1[0] + r1[1] + r1[2] + r1[3];
  s2 = r2[0] + r2[1] + r2[2] + r2[3];
  const float mean = s1 * (1.0f / 1024.0f);
  float var = s2 * (1.0f / 1024.0f) - mean * mean;
  var = fmaxf(var, 0.0f);
  const float inv = rsqrtf(var + 1e-14f);
  const float g = gamma[gidx], be = beta[gidx];
  float o0 = (v0 - mean) * inv * g + be;
  float o1 = (v1 - mean) * inv * g + be;
  float o2 = (v2 - mean) * inv * g + be;
  float o3 = (v3 - mean) * inv * g + be;
  float4 ov = {o0, o1, o2, o3};
  *(float4*)(xout + base) = ov;
  if (extf) {
    *(float4*)(extf + base) = ov;
  } else {
    bf16_t h0, l0, h1, l1, h2, l2, h3, l3;
    split2(o0, h0, l0); split2(o1, h1, l1);
    split2(o2, h2, l2); split2(o3, h3, l3);
    bf16x4v hv = {h0, h1, h2, h3};
    bf16x4v lv = {l0, l1, l2, l3};
    *(bf16x4v*)(xbh + base) = hv;
    *(bf16x4v*)(xbl + base) = lv;
  }
}

// fp32 input x -> X32 (fp32 copy) + split XB
__global__ __launch_bounds__(256) void cast_f2b(const float* __restrict__ in) {
  float* out = (float*)(g_ws + OFF_X32);
  bf16_t* outh = (bf16_t*)(g_ws + OFF_XB_HI);
  bf16_t* outl = (bf16_t*)(g_ws + OFF_XB_LO);
  long i = ((long)blockIdx.x * 256 + threadIdx.x) * 4;
  float4 v = *(const float4*)(in + i);
  *(float4*)(out + i) = v;
  bf16_t h0, l0, h1, l1, h2, l2, h3, l3;
  split2(v.x, h0, l0); split2(v.y, h1, l1);
  split2(v.z, h2, l2); split2(v.w, h3, l3);
  bf16x4v hv = {h0, h1, h2, h3};
  bf16x4v lv = {l0, l1, l2, l3};
  *(bf16x4v*)(outh + i) = hv;
  *(bf16x4v*)(outl + i) = lv;
}

// tiled transpose+split: out[c*R + r] = split(in[r*C + c]). block (32,8).
__global__ __launch_bounds__(256) void transp_split(
    const float* __restrict__ in, size_t oh_off, size_t ol_off, int R, int C) {
  bf16_t* oh = (bf16_t*)(g_ws + oh_off);
  bf16_t* ol = (bf16_t*)(g_ws + ol_off);
  __shared__ float tile[32][33];
  const int tx = threadIdx.x, ty = threadIdx.y;
  const int c0 = blockIdx.x * 32, r0 = blockIdx.y * 32;
#pragma unroll
  for (int j = 0; j < 4; ++j)
    tile[ty + j * 8][tx] = in[(long)(r0 + ty + j * 8) * C + c0 + tx];
  __syncthreads();
#pragma unroll
  for (int j = 0; j < 4; ++j) {
    float v = tile[tx][ty + j * 8];
    bf16_t h, l;
    split2(v, h, l);
    long off = (long)(c0 + ty + j * 8) * R + r0 + tx;
    oh[off] = h;
    ol[off] = l;
  }
}

// QKV weight repack: Wq/Wk/Wv[h,d,dk] -> WQKV[n = mat*1024 + h*128 + dk][d]
// grid (4, 32, 24): z = mat*8 + h. block (32,8).
__global__ __launch_bounds__(256) void qkvw_trans(
    const float* __restrict__ Wq, const float* __restrict__ Wk,
    const float* __restrict__ Wv) {
  bf16_t* oh = (bf16_t*)(g_ws + OFF_WQKV_HI);
  bf16_t* ol = (bf16_t*)(g_ws + OFF_WQKV_LO);
  __shared__ float tile[32][33];
  const int tx = threadIdx.x, ty = threadIdx.y;
  const int z = blockIdx.z, mat = z >> 3, h = z & 7;
  const float* src = (mat == 0 ? Wq : (mat == 1 ? Wk : Wv)) + h * 131072;
  const int c0 = blockIdx.x * 32, r0 = blockIdx.y * 32;  // c: dk, r: d
#pragma unroll
  for (int j = 0; j < 4; ++j)
    tile[ty + j * 8][tx] = src[(r0 + ty + j * 8) * 128 + c0 + tx];
  __syncthreads();
  const int nbase = mat * 1024 + h * 128;
#pragma unroll
  for (int j = 0; j < 4; ++j) {
    float v = tile[tx][ty + j * 8];
    bf16_t hh, ll;
    split2(v, hh, ll);
    long off = (long)(nbase + c0 + ty + j * 8) * 1024 + r0 + tx;
    oh[off] = hh;
    ol[off] = ll;
  }
}

// V transpose: VT[bh,v,s] = QKV[(b*1024+s)*3072 + 2048 + h*128 + v] (hi & lo)
// grid (32 s-tiles, 4 v-tiles, 32 bh). block (32,8).
__global__ __launch_bounds__(256) void vt_trans() {
  const bf16_t* QKVh = (const bf16_t*)(g_ws + OFF_QKV_HI);
  const bf16_t* QKVl = (const bf16_t*)(g_ws + OFF_QKV_LO);
  bf16_t* VTh = (bf16_t*)(g_ws + OFF_VT_HI);
  bf16_t* VTl = (bf16_t*)(g_ws + OFF_VT_LO);
  __shared__ bf16_t th[32][34];
  __shared__ bf16_t tl[32][34];
  const int tx = threadIdx.x, ty = threadIdx.y;
  const int bh = blockIdx.z, b = bh >> 3, h = bh & 7;
  const int s0 = blockIdx.x * 32, v0 = blockIdx.y * 32;
#pragma unroll
  for (int j = 0; j < 4; ++j) {
    long src = ((long)(b * 1024) + s0 + ty + j * 8) * 3072 + 2048 + h * 128 + v0 + tx;
    th[ty + j * 8][tx] = QKVh[src];
    tl[ty + j * 8][tx] = QKVl[src];
  }
  __syncthreads();
#pragma unroll
  for (int j = 0; j < 4; ++j) {
    long off = (long)bh * 131072 + (long)(v0 + ty + j * 8) * 1024 + s0 + tx;
    VTh[off] = th[tx][ty + j * 8];
    VTl[off] = tl[tx][ty + j * 8];
  }
}

// ---------------------------------------------------------------------------
extern "C" void kernel_launch(void* const* d_in, const int* in_sizes, int n_in,
                              void* d_out, int out_size, void* d_ws, size_t ws_size,
                              hipStream_t stream) {
  const float* x_in = (const float*)d_in[0];
  const float* mask = (const float*)d_in[1];
  const float* Wq = (const float*)d_in[2];
  const float* Wk = (const float*)d_in[3];
  const float* Wv = (const float*)d_in[4];
  const float* Wo = (const float*)d_in[5];
  const float* W1 = (const float*)d_in[6];
  const float* b1 = (const float*)d_in[7];
  const float* W2 = (const float*)d_in[8];
  const float* b2 = (const float*)d_in[9];
  const float* gamma = (const float*)d_in[10];
  const float* beta = (const float*)d_in[11];
  float* out = (float*)d_out;
  (void)d_ws; (void)ws_size; (void)in_sizes; (void)n_in; (void)out_size;

  const dim3 tb(32, 8);
  cast_f2b<<<4096, 256, 0, stream>>>(x_in);

  for (int l = 0; l < 2; ++l) {
    qkvw_trans<<<dim3(4, 32, 24), tb, 0, stream>>>(
        Wq + (long)l * 1048576, Wk + (long)l * 1048576, Wv + (long)l * 1048576);
    transp_split<<<dim3(32, 32), tb, 0, stream>>>(Wo + (long)l * 1048576,
                                                  OFF_WO_HI, OFF_WO_LO, 1024, 1024);
    transp_split<<<dim3(64, 32), tb, 0, stream>>>(W1 + (long)l * 2097152,
                                                  OFF_W1_HI, OFF_W1_LO, 1024, 2048);
    transp_split<<<dim3(32, 64), tb, 0, stream>>>(W2 + (long)l * 2097152,
                                                  OFF_W2_HI, OFF_W2_LO, 2048, 1024);

    // fused QKV GEMM: [4096,1024] @ [3072,1024]^T -> [4096,3072]
    gemm_bt<1><<<dim3(24, 32), 512, 0, stream>>>(
        OFF_XB_HI, OFF_XB_LO, OFF_WQKV_HI, OFF_WQKV_LO,
        OFF_QKV_HI, OFF_QKV_LO, nullptr, 4096, 3072, 1024);
    vt_trans<<<dim3(32, 4, 32), tb, 0, stream>>>();
    attn_kernel<<<dim3(16, 32), 256, 0, stream>>>(mask);
    gemm_bt<0><<<dim3(8, 32), 512, 0, stream>>>(
        OFF_CONC_HI, OFF_CONC_LO, OFF_WO_HI, OFF_WO_LO,
        OFF_TMP, 0, nullptr, 4096, 1024, 1024);
    ln_kernel<<<4096, 256, 0, stream>>>(gamma, beta, 2 * l, nullptr);
    gemm_bt<2><<<dim3(16, 32), 512, 0, stream>>>(
        OFF_XB_HI, OFF_XB_LO, OFF_W1_HI, OFF_W1_LO,
        OFF_H_HI, OFF_H_LO, b1 + l * 2048, 4096, 2048, 1024);
    gemm_bt<3><<<dim3(8, 32), 512, 0, stream>>>(
        OFF_H_HI, OFF_H_LO, OFF_W2_HI, OFF_W2_LO,
        OFF_TMP, 0, b2 + l * 1024, 4096, 1024, 2048);
    ln_kernel<<<4096, 256, 0, stream>>>(gamma, beta, 2 * l + 1,
                                        (l == 1) ? out : nullptr);
  }
}